// Round 11
// baseline (372.014 us; speedup 1.0000x reference)
//
#include <hip/hip_runtime.h>

// EdgeBlock: out = relu(concat(xn[src], xn[dst], xe) @ W1 + b1) @ W2 + b2
// R11 = R10 with the stageA_f32 swizzle fix (load group j, store slot j^rb;
// R10 XORed both sides -> identity -> scrambled edge-segment A fragments).
// Geometry: BM=256 BN=256 BK=64, 512thr, 8 waves (2Mx4N), acc[8][4],
// 64 MFMA/wave/K-step. 12 GEMM1 steps + 4 GEMM2 steps (B direct ping-pong).

typedef __attribute__((ext_vector_type(8))) short short8;
typedef __attribute__((ext_vector_type(4))) float f32x4;
typedef __attribute__((address_space(1))) unsigned int* gp1_t;
typedef __attribute__((address_space(3))) unsigned int* lp3_t;

#define SMEM_SZ 131072   // A dbuf 2x32KB @0, B dbuf 2x32KB @64KB; Hs/outst alias
#define LDO 260

__device__ __forceinline__ unsigned short f2b(float f) {
  unsigned int u = __float_as_uint(f);
  return (unsigned short)((u + 0x7FFFu + ((u >> 16) & 1u)) >> 16);
}
__device__ __forceinline__ unsigned int f2b2(float lo, float hi) {
  return (unsigned int)f2b(lo) | ((unsigned int)f2b(hi) << 16);
}
__device__ __forceinline__ void gload16(const void* g, void* l) {
  __builtin_amdgcn_global_load_lds((gp1_t)g, (lp3_t)l, 16, 0, 0);
}

// Pack W[K][256] -> steps of [256 n][8 s][8 j] bf16 (32KB/step).
// Slot s of row n holds source k-group (s ^ (n&7)) within the step.
__global__ void prep_w_kernel(const float* __restrict__ w,
                              unsigned short* __restrict__ wp, int total) {
  int i = blockIdx.x * 256 + threadIdx.x;
  if (i >= total) return;
  int step = i >> 14;
  int rem = i & 16383;
  int n = rem >> 6;
  int s = (rem >> 3) & 7;
  int j = i & 7;
  int k = step * 64 + (((s ^ (n & 7)) << 3) | j);
  wp[i] = f2b(w[(size_t)k * 256 + n]);
}

__global__ void conv_bf16_kernel(const float* __restrict__ x,
                                 unsigned short* __restrict__ y, int n4) {
  int i = blockIdx.x * 256 + threadIdx.x;
  if (i >= n4) return;
  float4 v = ((const float4*)x)[i];
  ushort4 u;
  u.x = f2b(v.x); u.y = f2b(v.y); u.z = f2b(v.z); u.w = f2b(v.w);
  ((ushort4*)y)[i] = u;
}

__global__ __launch_bounds__(512) void edge_mlp_full(
    const float* __restrict__ xnode, const float* __restrict__ xedge,
    const int* __restrict__ eidx,
    const unsigned short* __restrict__ nodeb, int use_nodeb,
    const unsigned short* __restrict__ wt1p, const float* __restrict__ b1,
    const unsigned short* __restrict__ wt2p, const float* __restrict__ b2,
    float* __restrict__ out, int E) {
  __shared__ __align__(16) char smem[SMEM_SZ];

  const int t = threadIdx.x, w = t >> 6, l = t & 63;
  const int lr = l & 15, lk = l >> 4;
  const int wr = w >> 2, wc = w & 3;       // 2(M) x 4(N) wave grid
  const int ebase = blockIdx.x * 256;

  // --- staging row ids ---
  // node gather (gload16): wave w, instr q, lane l -> row 32w+8q+(l>>3)
  int nsrcq[4], ndstq[4];
#pragma unroll
  for (int q = 0; q < 4; ++q) {
    int rq = 32 * w + 8 * q + (l >> 3);
    int eq = ebase + rq;
    if (eq >= E) eq = E - 1;
    nsrcq[q] = eidx[eq];
    ndstq[q] = eidx[E + eq];
  }
  // lane-constant source swizzle: slot (l&7) must hold group (l&7)^(row&7),
  // and row&7 == (l>>3)&7 for every gather instr.
  const int swz16 = ((l & 7) ^ ((l >> 3) & 7)) << 4;
  // reg-stage path (edge f32; node-f32 fallback): thread t -> row t>>1
  const int r2 = t >> 1;
  int e2 = ebase + r2;
  if (e2 >= E) e2 = E - 1;
  const int ns2 = eidx[e2], nd2 = eidx[E + e2];

  f32x4 acc[8][4];
#pragma unroll
  for (int i = 0; i < 8; ++i)
#pragma unroll
    for (int j = 0; j < 4; ++j) acc[i][j] = (f32x4)0.0f;

  // ---- staging helpers ----
  auto stageB = [&](int step, int buf) {   // 32KB packed W1 step, linear
    const char* g = (const char*)wt1p + (size_t)step * 32768 + (t << 4);
    char* d = smem + 65536 + buf * 32768 + (w << 10) + (l << 4);
#pragma unroll
    for (int q = 0; q < 4; ++q) gload16(g + q * 8192, d + q * 8192);
  };
  auto stageA_node = [&](int s, int buf) { // bf16 table gather, swizzled src
    const int colb = (s & 3) * 128;
    char* d = smem + buf * 32768 + (w << 12) + (l << 4);
#pragma unroll
    for (int q = 0; q < 4; ++q) {
      const int nid = (s < 4) ? nsrcq[q] : ndstq[q];
      gload16((const char*)nodeb + (size_t)nid * 512 + colb + swz16,
              d + (q << 10));
    }
  };
  auto stageA_f32 = [&](const float* base, int rowid, int coloff, int buf) {
    const int rb = r2 & 7;
    float4 v[8];
#pragma unroll
    for (int jj = 0; jj < 4; ++jj) {
      const int j = (t & 1) * 4 + jj;
      const float* p = base + (size_t)rowid * 256 + coloff + j * 8;  // logical group j
      v[2 * jj] = ((const float4*)p)[0];
      v[2 * jj + 1] = ((const float4*)p)[1];
    }
#pragma unroll
    for (int jj = 0; jj < 4; ++jj) {
      const int j = (t & 1) * 4 + jj;
      uint4 u;
      u.x = f2b2(v[2 * jj].x, v[2 * jj].y);
      u.y = f2b2(v[2 * jj].z, v[2 * jj].w);
      u.z = f2b2(v[2 * jj + 1].x, v[2 * jj + 1].y);
      u.w = f2b2(v[2 * jj + 1].z, v[2 * jj + 1].w);
      // logical group j stored at physical slot j^(row&7)
      *(uint4*)(smem + buf * 32768 + r2 * 128 + ((j ^ rb) << 4)) = u;
    }
  };
  auto stageA = [&](int s, int buf) {      // s = K-step 0..11
    if (s < 8) {
      if (use_nodeb) stageA_node(s, buf);
      else stageA_f32(xnode, (s < 4) ? ns2 : nd2, (s & 3) * 64, buf);
    } else {
      stageA_f32(xedge, e2, (s - 8) * 64, buf);
    }
  };
  auto compute = [&](int k) {
    const char* A = smem + (k & 1) * 32768;
    const char* B = smem + 65536 + (k & 1) * 32768;
    __builtin_amdgcn_s_setprio(1);
#pragma unroll
    for (int ks = 0; ks < 2; ++ks) {
      short8 bf[4];
#pragma unroll
      for (int ni = 0; ni < 4; ++ni) {
        const int n = wc * 64 + ni * 16 + lr;
        bf[ni] = *(const short8*)(B + n * 128 + (((ks * 4 + lk) ^ (n & 7)) << 4));
      }
#pragma unroll
      for (int mi = 0; mi < 8; ++mi) {
        const int m = wr * 128 + mi * 16 + lr;
        short8 af = *(const short8*)(A + m * 128 + (((ks * 4 + lk) ^ (m & 7)) << 4));
#pragma unroll
        for (int ni = 0; ni < 4; ++ni)
          acc[mi][ni] = __builtin_amdgcn_mfma_f32_16x16x32_bf16(
              af, bf[ni], acc[mi][ni], 0, 0, 0);
      }
    }
    __builtin_amdgcn_s_setprio(0);
  };

  // ---- GEMM1: 12 K-steps of 64, A/B dbuf ----
  stageA(0, 0);
  stageB(0, 0);
  __syncthreads();
  for (int k = 0; k < 12; ++k) {
    if (k + 1 < 12) {
      stageB(k + 1, (k + 1) & 1);
      stageA(k + 1, (k + 1) & 1);
    }
    compute(k);
    __syncthreads();
  }

  // ---- bias + ReLU -> Hs (XOR-swizzled paired u32 writes; aliases A/B) ----
  char* Hs = smem;
#pragma unroll
  for (int ni = 0; ni < 4; ++ni) {
    const int col = wc * 64 + ni * 16 + lr;
    const float bias = b1[col];
    const int cole = col & ~1;
    const int chunk = cole >> 3;
    const int cb = (cole & 6) * 2;
#pragma unroll
    for (int mi = 0; mi < 8; ++mi) {
      float v[4], p[4];
#pragma unroll
      for (int r = 0; r < 4; ++r) {
        float x = acc[mi][ni][r] + bias;
        v[r] = x > 0.f ? x : 0.f;
        acc[mi][ni][r] = 0.f;
      }
#pragma unroll
      for (int r = 0; r < 4; ++r) p[r] = __shfl_xor(v[r], 1, 64);
      const int r0 = (lr & 1) ? 2 : 0;
#pragma unroll
      for (int rr = 0; rr < 2; ++rr) {
        const int r = r0 + rr;
        const int row = wr * 128 + mi * 16 + lk * 4 + r;
        const float lo = (lr & 1) ? p[r] : v[r];
        const float hi = (lr & 1) ? v[r] : p[r];
        *(unsigned int*)(Hs + row * 512 + ((chunk ^ (row & 7)) << 4) + cb) =
            f2b2(lo, hi);
      }
    }
  }
  __syncthreads();

  // ---- GEMM2: 4 K-steps of 64; A from Hs, B direct global (ping-pong) ----
  short8 bfA[4], bfB[4];
  auto loadB2 = [&](int pair, short8 (&bf)[4]) {   // pair = u*2+ks, 0..7
    const char* wb = (const char*)wt2p + (pair >> 1) * 32768;
    const int ksl = (pair & 1) * 4 + lk;
#pragma unroll
    for (int ni = 0; ni < 4; ++ni) {
      const int n = wc * 64 + ni * 16 + lr;
      bf[ni] = *(const short8*)(wb + n * 128 + ((ksl ^ (n & 7)) << 4));
    }
  };
  auto mfmaH = [&](int pair, short8 (&bf)[4]) {
    const int j = (pair >> 1) * 8 + (pair & 1) * 4 + lk;  // H col-group 0..31
    __builtin_amdgcn_s_setprio(1);
#pragma unroll
    for (int mi = 0; mi < 8; ++mi) {
      const int m = wr * 128 + mi * 16 + lr;
      short8 af = *(const short8*)(Hs + m * 512 + ((j ^ (m & 7)) << 4));
#pragma unroll
      for (int ni = 0; ni < 4; ++ni)
        acc[mi][ni] = __builtin_amdgcn_mfma_f32_16x16x32_bf16(
            af, bf[ni], acc[mi][ni], 0, 0, 0);
    }
    __builtin_amdgcn_s_setprio(0);
  };
  loadB2(0, bfA);
#pragma unroll
  for (int pair = 0; pair < 8; pair += 2) {
    if (pair + 1 < 8) loadB2(pair + 1, bfB);
    mfmaH(pair, bfA);
    if (pair + 2 < 8) loadB2(pair + 2, bfA);
    if (pair + 1 < 8) mfmaH(pair + 1, bfB);
  }

  // ---- bias + coalesced f32 store via LDS (four 64-row passes) ----
  float* outst = (float*)smem;
#pragma unroll
  for (int p = 0; p < 4; ++p) {
    __syncthreads();
    if (wr == (p >> 1)) {
#pragma unroll
      for (int ni = 0; ni < 4; ++ni) {
        const int col = wc * 64 + ni * 16 + lr;
        const float bias = b2[col];
#pragma unroll
        for (int mh = 0; mh < 4; ++mh) {
          const int mi = (p & 1) * 4 + mh;
#pragma unroll
          for (int r = 0; r < 4; ++r)
            outst[(mh * 16 + lk * 4 + r) * LDO + col] = acc[mi][ni][r] + bias;
        }
      }
    }
    __syncthreads();
#pragma unroll
    for (int it = 0; it < 8; ++it) {
      const int idx = it * 2048 + t * 4;
      const int lrow = idx >> 8;
      const int cc = idx & 255;
      const int grow = ebase + p * 64 + lrow;
      if (grow < E)
        *(float4*)(out + (size_t)grow * 256 + cc) =
            *(const float4*)(outst + lrow * LDO + cc);
    }
  }
}

extern "C" void kernel_launch(void* const* d_in, const int* in_sizes, int n_in,
                              void* d_out, int out_size, void* d_ws, size_t ws_size,
                              hipStream_t stream) {
  const float* xnode = (const float*)d_in[0];
  const float* xedge = (const float*)d_in[1];
  const int* eidx = (const int*)d_in[2];
  const float* W1 = (const float*)d_in[3];
  const float* b1 = (const float*)d_in[4];
  const float* W2 = (const float*)d_in[5];
  const float* b2 = (const float*)d_in[6];
  float* out = (float*)d_out;

  const int NN = in_sizes[0] / 256;   // 50000
  const int E = in_sizes[1] / 256;    // 300000

  char* ws = (char*)d_ws;
  unsigned short* wt1p = (unsigned short*)ws;                   // 12 x 32KB
  unsigned short* wt2p = (unsigned short*)(ws + 12 * 32768);    //  4 x 32KB
  unsigned short* nodeb = (unsigned short*)(ws + 16 * 32768);   // NN*512B
  const size_t need_tbl = (size_t)16 * 32768 + (size_t)NN * 512;
  const int use_nodeb = (ws_size >= need_tbl) ? 1 : 0;

  prep_w_kernel<<<(12 * 16384 + 255) / 256, 256, 0, stream>>>(W1, wt1p,
                                                              12 * 16384);
  prep_w_kernel<<<(4 * 16384 + 255) / 256, 256, 0, stream>>>(W2, wt2p,
                                                             4 * 16384);
  if (use_nodeb) {
    const int n4 = NN * 64;
    conv_bf16_kernel<<<(n4 + 255) / 256, 256, 0, stream>>>(xnode, nodeb, n4);
  }

  const int grid = (E + 255) / 256;
  edge_mlp_full<<<grid, 512, 0, stream>>>(xnode, xedge, eidx, nodeb, use_nodeb,
                                          wt1p, b1, wt2p, b2, out, E);
}